// Round 15
// baseline (234.406 us; speedup 1.0000x reference)
//
#include <hip/hip_runtime.h>
#include <hip/hip_fp8.h>

#define N_NODES 50000
#define N_EDGES 800000
#define D_IN 128
#define HIDDEN 128
#define N_CLASSES 40

#define M_PAD 50048      // 782 * 64
#define CAP 64           // bucket capacity per node (deg ~ Binom(800k,1/50k))
#define EDGE_BATCH_BLOCKS 391  // 391*256*8 = 800768 >= 800000

typedef __attribute__((ext_vector_type(8))) short short8;
typedef __attribute__((ext_vector_type(4))) float floatx4;

static __device__ __forceinline__ unsigned short f2bf(float f) {
    unsigned u = __float_as_uint(f);
    u = (u + 0x7fffu + ((u >> 16) & 1u)) >> 16;  // RNE
    return (unsigned short)u;
}
static __device__ __forceinline__ float bf2f(unsigned short b) {
    return __uint_as_float(((unsigned)b) << 16);
}
// fp8 e4m3 (OCP, gfx950) encode/decode via HIP type (HW cvt on gfx950)
static __device__ __forceinline__ unsigned char f2fp8(float v) {
    __hip_fp8_e4m3 t(v);
    return (unsigned char)t.__x;
}
static __device__ __forceinline__ float fp82f(unsigned char b) {
    __hip_fp8_e4m3 t;
    t.__x = (__hip_fp8_storage_t)b;
    return (float)t;
}

// ---------------------------------------------------------------------------
// prep: W1 -> transposed bf16, W2 -> transposed bf16, cnt -> 0.
// ---------------------------------------------------------------------------
#define KP_W1 128                      // 32768 elems / 256
#define KP_W2 40                       // 10240 elems / 256
#define KP_CNT 196                     // 50000 ints / 256
#define KP_GRID (KP_W1 + KP_W2 + KP_CNT)

__global__ __launch_bounds__(256) void prep_kernel(
    const float* __restrict__ W1l, const float* __restrict__ W1r,
    unsigned short* __restrict__ Wt1, const float* __restrict__ W2l,
    const float* __restrict__ W2r, unsigned short* __restrict__ Wt2,
    int* __restrict__ cnt) {
    int b = blockIdx.x;
    int t = threadIdx.x;
    if (b < KP_W1) {
        int i = b * 256 + t;  // < 256*128
        int n = i >> 7, k = i & 127;
        float v = (n < 128) ? W1l[k * 128 + n] : W1r[k * 128 + (n - 128)];
        Wt1[n * 128 + k] = f2bf(v);
    } else if (b < KP_W1 + KP_W2) {
        int i = (b - KP_W1) * 256 + t;  // < 80*128
        int n = i >> 7, k = i & 127;
        float v = (n < 40) ? W2l[k * 40 + n] : W2r[k * 40 + (n - 40)];
        Wt2[n * 128 + k] = f2bf(v);
    } else {
        int i = (b - KP_W1 - KP_W2) * 256 + t;
        if (i < N_NODES) cnt[i] = 0;
    }
}

// ---------------------------------------------------------------------------
// SINGLE-PASS adjacency build: fixed-capacity USHORT buckets, ONE atomic per
// edge. ~45 us is the measured 800k-random-RMW HW floor (r6/r8/r9/r10/r11
// invariant — insensitive to ILP, striping, entry width). Do not add passes.
// Overflow (p >= CAP) is statistically impossible (P(deg>64) ~ e-20) and
// degrades to a dropped edge, not UB.
// ---------------------------------------------------------------------------
__global__ __launch_bounds__(256) void fill_bucket_kernel(
    const int* __restrict__ src, const int* __restrict__ dst,
    int* __restrict__ cnt, unsigned short* __restrict__ bucket) {
    int i0 = (blockIdx.x * 256 + threadIdx.x) * 8;
    if (i0 >= N_EDGES) return;  // 800000 % 8 == 0 -> full groups only
    int4 d0 = *(const int4*)(dst + i0);
    int4 d1 = *(const int4*)(dst + i0 + 4);
    int4 s0 = *(const int4*)(src + i0);
    int4 s1 = *(const int4*)(src + i0 + 4);
    int p0 = atomicAdd(&cnt[d0.x], 1);
    int p1 = atomicAdd(&cnt[d0.y], 1);
    int p2 = atomicAdd(&cnt[d0.z], 1);
    int p3 = atomicAdd(&cnt[d0.w], 1);
    int p4 = atomicAdd(&cnt[d1.x], 1);
    int p5 = atomicAdd(&cnt[d1.y], 1);
    int p6 = atomicAdd(&cnt[d1.z], 1);
    int p7 = atomicAdd(&cnt[d1.w], 1);
    if (p0 < CAP) bucket[d0.x * CAP + p0] = (unsigned short)s0.x;
    if (p1 < CAP) bucket[d0.y * CAP + p1] = (unsigned short)s0.y;
    if (p2 < CAP) bucket[d0.z * CAP + p2] = (unsigned short)s0.z;
    if (p3 < CAP) bucket[d0.w * CAP + p3] = (unsigned short)s0.w;
    if (p4 < CAP) bucket[d1.x * CAP + p4] = (unsigned short)s1.x;
    if (p5 < CAP) bucket[d1.y * CAP + p5] = (unsigned short)s1.y;
    if (p6 < CAP) bucket[d1.z * CAP + p6] = (unsigned short)s1.z;
    if (p7 < CAP) bucket[d1.w * CAP + p7] = (unsigned short)s1.w;
}

// ---------------------------------------------------------------------------
// MFMA GEMM layer 1, restructured to gemm2's proven no-LDS/no-barrier form
// (r14: the LDS+barrier version ran 46 us at 24% occupancy with all pipes
// idle — latency-bound at 3128 waves; this form has 6256 waves).
// Wave = 16 rows x 128 cols (8 n-tiles, acc 32 VGPRs); blockIdx.y picks the
// column half: y=0 -> ylb fp8 (cols 0..127), y=1 -> yrb bf16 (cols 128..255).
// Lane loads 8 fp32 of row m0+r per kc and packs bf16 inline (RNE — output
// bit-identical to r12/r14). x read 2x total (once per col-half) — cheap vs
// the 2x wave parallelism gained (r10's failure was 4x SAME-wave redundancy).
// Wave layout (m89/m120-verified): A[m=lane&15][k=quad*8+j],
// B[k=quad*8+j][n=lane&15], D col=lane&15, row=quad*4+reg.
// ---------------------------------------------------------------------------
__global__ __launch_bounds__(256) void gemm1_mfma_kernel(
    const float* __restrict__ x, const unsigned short* __restrict__ Wt,
    unsigned char* __restrict__ ylb, unsigned short* __restrict__ yrb) {
    const int wave = threadIdx.x >> 6;
    const int lane = threadIdx.x & 63;
    const int r = lane & 15, q = lane >> 4;
    const int m0 = blockIdx.x * 64 + wave * 16;
    const int nbase = blockIdx.y * 128;  // 0 (ylb) or 128 (yrb)

    floatx4 acc[8];
#pragma unroll
    for (int i = 0; i < 8; i++) acc[i] = (floatx4){0.f, 0.f, 0.f, 0.f};

    int gr_a = m0 + r;
    if (gr_a >= N_NODES) gr_a = N_NODES - 1;
    const float* xrow = x + (size_t)gr_a * 128;

#pragma unroll
    for (int kc = 0; kc < 128; kc += 32) {
        float4 v0 = *(const float4*)(xrow + kc + q * 8);
        float4 v1 = *(const float4*)(xrow + kc + q * 8 + 4);
        uint4 u;
        u.x = (unsigned)f2bf(v0.x) | ((unsigned)f2bf(v0.y) << 16);
        u.y = (unsigned)f2bf(v0.z) | ((unsigned)f2bf(v0.w) << 16);
        u.z = (unsigned)f2bf(v1.x) | ((unsigned)f2bf(v1.y) << 16);
        u.w = (unsigned)f2bf(v1.z) | ((unsigned)f2bf(v1.w) << 16);
        short8 a = *(short8*)&u;
        short8 b[8];
#pragma unroll
        for (int ni = 0; ni < 8; ni++)
            b[ni] = *(const short8*)(Wt + (size_t)(nbase + ni * 16 + r) * 128 + kc + q * 8);
#pragma unroll
        for (int ni = 0; ni < 8; ni++)
            acc[ni] = __builtin_amdgcn_mfma_f32_16x16x32_bf16(a, b[ni], acc[ni], 0, 0, 0);
    }

    int rowb = m0 + q * 4;
    if (blockIdx.y == 0) {
#pragma unroll
        for (int ni = 0; ni < 8; ni++) {
            int col = ni * 16 + r;
#pragma unroll
            for (int reg = 0; reg < 4; reg++) {
                int gr = rowb + reg;
                if (gr < N_NODES) ylb[(size_t)gr * 128 + col] = f2fp8(acc[ni][reg]);
            }
        }
    } else {
#pragma unroll
        for (int ni = 0; ni < 8; ni++) {
            int col = ni * 16 + r;
#pragma unroll
            for (int reg = 0; reg < 4; reg++) {
                int gr = rowb + reg;
                if (gr < N_NODES) yrb[(size_t)gr * 128 + col] = f2bf(acc[ni][reg]);
            }
        }
    }
}

// ---------------------------------------------------------------------------
// MFMA GEMM layer 2 (separate — r13 fusion with agg_relu1 regressed 218->238:
// tile-shaped fusion cut gather wave-parallelism 50k->3k): [hb 50048x128
// bf16] @ [Wt2 80x128 bf16] -> cols 0..39 -> zlb bf16, cols 40..79 -> zrb.
// ---------------------------------------------------------------------------
__global__ __launch_bounds__(256) void gemm2_mfma_kernel(
    const unsigned short* __restrict__ hb, const unsigned short* __restrict__ Wt,
    unsigned short* __restrict__ zlb, unsigned short* __restrict__ zrb) {
    const int wave = threadIdx.x >> 6;
    const int lane = threadIdx.x & 63;
    const int r = lane & 15, q = lane >> 4;
    const int m0 = blockIdx.x * 64 + wave * 16;

    floatx4 acc[5];
#pragma unroll
    for (int i = 0; i < 5; i++) acc[i] = (floatx4){0.f, 0.f, 0.f, 0.f};

#pragma unroll
    for (int kc = 0; kc < 128; kc += 32) {
        short8 a = *(const short8*)(hb + (size_t)(m0 + r) * 128 + kc + q * 8);
        short8 b[5];
#pragma unroll
        for (int ni = 0; ni < 5; ni++)
            b[ni] = *(const short8*)(Wt + (size_t)(ni * 16 + r) * 128 + kc + q * 8);
#pragma unroll
        for (int ni = 0; ni < 5; ni++)
            acc[ni] = __builtin_amdgcn_mfma_f32_16x16x32_bf16(a, b[ni], acc[ni], 0, 0, 0);
    }

    int rowb = m0 + q * 4;
#pragma unroll
    for (int ni = 0; ni < 5; ni++) {
        int col = ni * 16 + r;
#pragma unroll
        for (int reg = 0; reg < 4; reg++) {
            int gr = rowb + reg;
            if (gr < N_NODES) {
                unsigned short v = f2bf(acc[ni][reg]);
                if (col < 40)
                    zlb[(size_t)gr * 40 + col] = v;
                else
                    zrb[(size_t)gr * 40 + (col - 40)] = v;
            }
        }
    }
}

// ---------------------------------------------------------------------------
// Fused agg + epilogue layer 1, FP8 gather (128 B/row), 8-deep unroll.
// ONE NODE PER WAVE (50k waves — gather throughput comes from wave count;
// r13's 16-nodes-per-wave fusion proved this the hard way):
//   h[n] = relu( (1/max(cnt,1)) * sum_j yl[bucket[n][j]] + yr[n] + b1 )
// ---------------------------------------------------------------------------
__global__ __launch_bounds__(256) void agg_relu1_kernel(
    const unsigned short* __restrict__ yl8, const int* __restrict__ cnt,
    const unsigned short* __restrict__ bucket, const float2* __restrict__ b12,
    const unsigned int* __restrict__ yru, unsigned int* __restrict__ hbu) {
    int n = blockIdx.x * 4 + (threadIdx.x >> 6);
    if (n >= N_NODES) return;
    int l = threadIdx.x & 63;
    int deg = cnt[n];
    int re = min(deg, CAP);
    const unsigned short* bk = bucket + n * CAP;
    float ax = 0.f, ay = 0.f, bx = 0.f, by = 0.f;
    int e = 0;
    for (; e + 7 < re; e += 8) {
        unsigned short u[8];
#pragma unroll
        for (int j = 0; j < 8; j++) {
            int s = bk[e + j];
            u[j] = yl8[(size_t)s * 64 + l];
        }
#pragma unroll
        for (int j = 0; j < 8; j += 2) {
            ax += fp82f(u[j] & 0xff); ay += fp82f(u[j] >> 8);
            bx += fp82f(u[j + 1] & 0xff); by += fp82f(u[j + 1] >> 8);
        }
    }
    for (; e + 3 < re; e += 4) {
        int s0 = bk[e + 0], s1 = bk[e + 1], s2 = bk[e + 2], s3 = bk[e + 3];
        unsigned short u0 = yl8[(size_t)s0 * 64 + l];
        unsigned short u1 = yl8[(size_t)s1 * 64 + l];
        unsigned short u2 = yl8[(size_t)s2 * 64 + l];
        unsigned short u3 = yl8[(size_t)s3 * 64 + l];
        ax += fp82f(u0 & 0xff); ay += fp82f(u0 >> 8);
        bx += fp82f(u1 & 0xff); by += fp82f(u1 >> 8);
        ax += fp82f(u2 & 0xff); ay += fp82f(u2 >> 8);
        bx += fp82f(u3 & 0xff); by += fp82f(u3 >> 8);
    }
    for (; e < re; e++) {
        unsigned short u0 = yl8[(size_t)bk[e] * 64 + l];
        ax += fp82f(u0 & 0xff); ay += fp82f(u0 >> 8);
    }
    float inv = 1.0f / (float)max(deg, 1);
    unsigned ur = yru[(size_t)n * 64 + l];
    float2 b = b12[l];
    float ox = fmaxf((ax + bx) * inv + bf2f(ur & 0xffff) + b.x, 0.0f);
    float oy = fmaxf((ay + by) * inv + bf2f(ur >> 16) + b.y, 0.0f);
    hbu[(size_t)n * 64 + l] = (unsigned)f2bf(ox) | ((unsigned)f2bf(oy) << 16);
}

// ---------------------------------------------------------------------------
// Fused agg + epilogue layer 2 (bf16 z), bucket traversal:
//   out[n][c] = (1/max(cnt,1)) * sum_j zl[bucket[n][j]][c] + zr[n][c] + b2[c]
// ---------------------------------------------------------------------------
__global__ __launch_bounds__(256) void agg_out2_kernel(
    const unsigned short* __restrict__ zlb, const unsigned short* __restrict__ zrb,
    const int* __restrict__ cnt, const unsigned short* __restrict__ bucket,
    const float* __restrict__ b2, float* __restrict__ out) {
    int n = blockIdx.x * 4 + (threadIdx.x >> 6);
    if (n >= N_NODES) return;
    int c = threadIdx.x & 63;
    if (c >= N_CLASSES) return;
    int deg = cnt[n];
    int re = min(deg, CAP);
    const unsigned short* bk = bucket + n * CAP;
    float a0 = 0.f, a1 = 0.f;
    int e = 0;
    for (; e + 3 < re; e += 4) {
        int s0 = bk[e + 0], s1 = bk[e + 1], s2 = bk[e + 2], s3 = bk[e + 3];
        float v0 = bf2f(zlb[(size_t)s0 * 40 + c]);
        float v1 = bf2f(zlb[(size_t)s1 * 40 + c]);
        float v2 = bf2f(zlb[(size_t)s2 * 40 + c]);
        float v3 = bf2f(zlb[(size_t)s3 * 40 + c]);
        a0 += v0 + v2;
        a1 += v1 + v3;
    }
    for (; e < re; e++) a0 += bf2f(zlb[(size_t)bk[e] * 40 + c]);
    float inv = 1.0f / (float)max(deg, 1);
    out[(size_t)n * 40 + c] =
        (a0 + a1) * inv + bf2f(zrb[(size_t)n * 40 + c]) + b2[c];
}

// ---------------------------------------------------------------------------
extern "C" void kernel_launch(void* const* d_in, const int* in_sizes, int n_in,
                              void* d_out, int out_size, void* d_ws, size_t ws_size,
                              hipStream_t stream) {
    const float* x   = (const float*)d_in[0];
    const int*   ei  = (const int*)d_in[1];   // [2, E]: src row then dst row
    const float* W1l = (const float*)d_in[2];
    const float* b1  = (const float*)d_in[3];
    const float* W1r = (const float*)d_in[4];
    const float* W2l = (const float*)d_in[5];
    const float* b2  = (const float*)d_in[6];
    const float* W2r = (const float*)d_in[7];
    float* out = (float*)d_out;

    const int* src = ei;
    const int* dst = ei + N_EDGES;

    // Workspace layout (bytes), strictly non-overlapping, 16B-aligned:
    //  cnt    @ 0            200,000   (pad to 262,144)
    //  bucket @ 262,144    6,400,000   ends  6,662,144  (ushort)
    //  Wt1    @ 6,662,144     65,536   ends  6,727,680
    //  Wt2    @ 6,727,680     20,480   ends  6,748,160
    //  hb     @ 6,748,160  12,812,288  ends 19,560,448  (M_PAD rows, bf16)
    //  ylb    @ 19,560,448  6,400,000  ends 25,960,448  (fp8 e4m3)
    //  yrb    @ 25,960,448 12,800,000  ends 38,760,448  (bf16)
    //  zlb    @ 38,760,448  4,000,000  ends 42,760,448  (bf16)
    //  zrb    @ 42,760,448  4,000,000  ends 46,760,448  (< 256 MiB)
    char* ws = (char*)d_ws;
    int* cnt               = (int*)(ws);
    unsigned short* bucket = (unsigned short*)(ws + 262144);
    unsigned short* Wt1    = (unsigned short*)(ws + 6662144);
    unsigned short* Wt2    = (unsigned short*)(ws + 6727680);
    unsigned short* hb     = (unsigned short*)(ws + 6748160);
    unsigned char*  ylb    = (unsigned char*)(ws + 19560448);
    unsigned short* yrb    = (unsigned short*)(ws + 25960448);
    unsigned short* zlb    = (unsigned short*)(ws + 38760448);
    unsigned short* zrb    = (unsigned short*)(ws + 42760448);

    // --- prep (weight transposes + cnt zero) + bucket build (1 atomic pass)
    prep_kernel<<<KP_GRID, 256, 0, stream>>>(W1l, W1r, Wt1, W2l, W2r, Wt2, cnt);
    fill_bucket_kernel<<<EDGE_BATCH_BLOCKS, 256, 0, stream>>>(src, dst, cnt,
                                                              bucket);

    const int AGG_BLOCKS = (N_NODES + 3) / 4;

    // --- Layer 1 (no-LDS gemm1: grid.y splits ylb/yrb col-halves)
    {
        dim3 grid(M_PAD / 64, 2);
        gemm1_mfma_kernel<<<grid, 256, 0, stream>>>(x, Wt1, ylb, yrb);
    }
    agg_relu1_kernel<<<AGG_BLOCKS, 256, 0, stream>>>(
        (const unsigned short*)ylb, cnt, bucket, (const float2*)b1,
        (const unsigned int*)yrb, (unsigned int*)hb);

    // --- Layer 2
    gemm2_mfma_kernel<<<M_PAD / 64, 256, 0, stream>>>(hb, Wt2, zlb, zrb);
    agg_out2_kernel<<<AGG_BLOCKS, 256, 0, stream>>>(
        zlb, zrb, cnt, bucket, b2, out);
}

// Round 16
// 233.406 us; speedup vs baseline: 1.0043x; 1.0043x over previous
//
#include <hip/hip_runtime.h>
#include <hip/hip_fp8.h>

#define N_NODES 50000
#define N_EDGES 800000
#define D_IN 128
#define HIDDEN 128
#define N_CLASSES 40

#define M_PAD 50048      // 782 * 64
#define CAP 64           // bucket capacity per node (deg ~ Binom(800k,1/50k))
#define EDGE_BATCH_BLOCKS 391  // 391*256*8 = 800768 >= 800000

typedef __attribute__((ext_vector_type(8))) short short8;
typedef __attribute__((ext_vector_type(4))) float floatx4;

static __device__ __forceinline__ unsigned short f2bf(float f) {
    unsigned u = __float_as_uint(f);
    u = (u + 0x7fffu + ((u >> 16) & 1u)) >> 16;  // RNE
    return (unsigned short)u;
}
static __device__ __forceinline__ float bf2f(unsigned short b) {
    return __uint_as_float(((unsigned)b) << 16);
}
// fp8 e4m3 (OCP, gfx950) encode/decode via HIP type (HW cvt on gfx950)
static __device__ __forceinline__ unsigned char f2fp8(float v) {
    __hip_fp8_e4m3 t(v);
    return (unsigned char)t.__x;
}
static __device__ __forceinline__ float fp82f(unsigned char b) {
    __hip_fp8_e4m3 t;
    t.__x = (__hip_fp8_storage_t)b;
    return (float)t;
}

// ---------------------------------------------------------------------------
// prep: W1 -> transposed bf16, W2 -> transposed bf16, cnt -> 0.
// ---------------------------------------------------------------------------
#define KP_W1 128                      // 32768 elems / 256
#define KP_W2 40                       // 10240 elems / 256
#define KP_CNT 196                     // 50000 ints / 256
#define KP_GRID (KP_W1 + KP_W2 + KP_CNT)

__global__ __launch_bounds__(256) void prep_kernel(
    const float* __restrict__ W1l, const float* __restrict__ W1r,
    unsigned short* __restrict__ Wt1, const float* __restrict__ W2l,
    const float* __restrict__ W2r, unsigned short* __restrict__ Wt2,
    int* __restrict__ cnt) {
    int b = blockIdx.x;
    int t = threadIdx.x;
    if (b < KP_W1) {
        int i = b * 256 + t;  // < 256*128
        int n = i >> 7, k = i & 127;
        float v = (n < 128) ? W1l[k * 128 + n] : W1r[k * 128 + (n - 128)];
        Wt1[n * 128 + k] = f2bf(v);
    } else if (b < KP_W1 + KP_W2) {
        int i = (b - KP_W1) * 256 + t;  // < 80*128
        int n = i >> 7, k = i & 127;
        float v = (n < 40) ? W2l[k * 40 + n] : W2r[k * 40 + (n - 40)];
        Wt2[n * 128 + k] = f2bf(v);
    } else {
        int i = (b - KP_W1 - KP_W2) * 256 + t;
        if (i < N_NODES) cnt[i] = 0;
    }
}

// ---------------------------------------------------------------------------
// SINGLE-PASS adjacency build: fixed-capacity USHORT buckets, ONE atomic per
// edge. ~45 us is the measured 800k-random-RMW HW floor (r6/r8/r9/r10/r11
// invariant — insensitive to ILP, striping, entry width). Do not add passes.
// Overflow (p >= CAP) is statistically impossible (P(deg>64) ~ e-20) and
// degrades to a dropped edge, not UB.
// ---------------------------------------------------------------------------
__global__ __launch_bounds__(256) void fill_bucket_kernel(
    const int* __restrict__ src, const int* __restrict__ dst,
    int* __restrict__ cnt, unsigned short* __restrict__ bucket) {
    int i0 = (blockIdx.x * 256 + threadIdx.x) * 8;
    if (i0 >= N_EDGES) return;  // 800000 % 8 == 0 -> full groups only
    int4 d0 = *(const int4*)(dst + i0);
    int4 d1 = *(const int4*)(dst + i0 + 4);
    int4 s0 = *(const int4*)(src + i0);
    int4 s1 = *(const int4*)(src + i0 + 4);
    int p0 = atomicAdd(&cnt[d0.x], 1);
    int p1 = atomicAdd(&cnt[d0.y], 1);
    int p2 = atomicAdd(&cnt[d0.z], 1);
    int p3 = atomicAdd(&cnt[d0.w], 1);
    int p4 = atomicAdd(&cnt[d1.x], 1);
    int p5 = atomicAdd(&cnt[d1.y], 1);
    int p6 = atomicAdd(&cnt[d1.z], 1);
    int p7 = atomicAdd(&cnt[d1.w], 1);
    if (p0 < CAP) bucket[d0.x * CAP + p0] = (unsigned short)s0.x;
    if (p1 < CAP) bucket[d0.y * CAP + p1] = (unsigned short)s0.y;
    if (p2 < CAP) bucket[d0.z * CAP + p2] = (unsigned short)s0.z;
    if (p3 < CAP) bucket[d0.w * CAP + p3] = (unsigned short)s0.w;
    if (p4 < CAP) bucket[d1.x * CAP + p4] = (unsigned short)s1.x;
    if (p5 < CAP) bucket[d1.y * CAP + p5] = (unsigned short)s1.y;
    if (p6 < CAP) bucket[d1.z * CAP + p6] = (unsigned short)s1.z;
    if (p7 < CAP) bucket[d1.w * CAP + p7] = (unsigned short)s1.w;
}

// ---------------------------------------------------------------------------
// MFMA GEMM layer 1, no-LDS/no-barrier form (r15; resubmitted unchanged in
// r16 to disambiguate a noisy run — fill_bucket's 5-round-invariant 45-47 us
// inflated to 49-54 in r15's run, implicating global slowdown, not this code).
// Wave = 16 rows x 128 cols (8 n-tiles); blockIdx.y picks the column half:
// y=0 -> ylb fp8 (cols 0..127), y=1 -> yrb bf16 (cols 128..255).
// 1564 blocks = 6256 waves vs r14's 3128 (which ran 46 us at 24% occupancy).
// Lane loads 8 fp32 of row m0+r per kc, packs bf16 inline (RNE, bit-identical
// output). x read 2x total — distinct rows per wave, no intra-wave redundancy
// (r10's failure was 4x SAME-rows redundancy).
// Wave layout (m89/m120-verified): A[m=lane&15][k=quad*8+j],
// B[k=quad*8+j][n=lane&15], D col=lane&15, row=quad*4+reg.
// ---------------------------------------------------------------------------
__global__ __launch_bounds__(256) void gemm1_mfma_kernel(
    const float* __restrict__ x, const unsigned short* __restrict__ Wt,
    unsigned char* __restrict__ ylb, unsigned short* __restrict__ yrb) {
    const int wave = threadIdx.x >> 6;
    const int lane = threadIdx.x & 63;
    const int r = lane & 15, q = lane >> 4;
    const int m0 = blockIdx.x * 64 + wave * 16;
    const int nbase = blockIdx.y * 128;  // 0 (ylb) or 128 (yrb)

    floatx4 acc[8];
#pragma unroll
    for (int i = 0; i < 8; i++) acc[i] = (floatx4){0.f, 0.f, 0.f, 0.f};

    int gr_a = m0 + r;
    if (gr_a >= N_NODES) gr_a = N_NODES - 1;
    const float* xrow = x + (size_t)gr_a * 128;

#pragma unroll
    for (int kc = 0; kc < 128; kc += 32) {
        float4 v0 = *(const float4*)(xrow + kc + q * 8);
        float4 v1 = *(const float4*)(xrow + kc + q * 8 + 4);
        uint4 u;
        u.x = (unsigned)f2bf(v0.x) | ((unsigned)f2bf(v0.y) << 16);
        u.y = (unsigned)f2bf(v0.z) | ((unsigned)f2bf(v0.w) << 16);
        u.z = (unsigned)f2bf(v1.x) | ((unsigned)f2bf(v1.y) << 16);
        u.w = (unsigned)f2bf(v1.z) | ((unsigned)f2bf(v1.w) << 16);
        short8 a = *(short8*)&u;
        short8 b[8];
#pragma unroll
        for (int ni = 0; ni < 8; ni++)
            b[ni] = *(const short8*)(Wt + (size_t)(nbase + ni * 16 + r) * 128 + kc + q * 8);
#pragma unroll
        for (int ni = 0; ni < 8; ni++)
            acc[ni] = __builtin_amdgcn_mfma_f32_16x16x32_bf16(a, b[ni], acc[ni], 0, 0, 0);
    }

    int rowb = m0 + q * 4;
    if (blockIdx.y == 0) {
#pragma unroll
        for (int ni = 0; ni < 8; ni++) {
            int col = ni * 16 + r;
#pragma unroll
            for (int reg = 0; reg < 4; reg++) {
                int gr = rowb + reg;
                if (gr < N_NODES) ylb[(size_t)gr * 128 + col] = f2fp8(acc[ni][reg]);
            }
        }
    } else {
#pragma unroll
        for (int ni = 0; ni < 8; ni++) {
            int col = ni * 16 + r;
#pragma unroll
            for (int reg = 0; reg < 4; reg++) {
                int gr = rowb + reg;
                if (gr < N_NODES) yrb[(size_t)gr * 128 + col] = f2bf(acc[ni][reg]);
            }
        }
    }
}

// ---------------------------------------------------------------------------
// MFMA GEMM layer 2 (separate — r13 fusion with agg_relu1 regressed 218->238:
// tile-shaped fusion cut gather wave-parallelism 50k->3k): [hb 50048x128
// bf16] @ [Wt2 80x128 bf16] -> cols 0..39 -> zlb bf16, cols 40..79 -> zrb.
// ---------------------------------------------------------------------------
__global__ __launch_bounds__(256) void gemm2_mfma_kernel(
    const unsigned short* __restrict__ hb, const unsigned short* __restrict__ Wt,
    unsigned short* __restrict__ zlb, unsigned short* __restrict__ zrb) {
    const int wave = threadIdx.x >> 6;
    const int lane = threadIdx.x & 63;
    const int r = lane & 15, q = lane >> 4;
    const int m0 = blockIdx.x * 64 + wave * 16;

    floatx4 acc[5];
#pragma unroll
    for (int i = 0; i < 5; i++) acc[i] = (floatx4){0.f, 0.f, 0.f, 0.f};

#pragma unroll
    for (int kc = 0; kc < 128; kc += 32) {
        short8 a = *(const short8*)(hb + (size_t)(m0 + r) * 128 + kc + q * 8);
        short8 b[5];
#pragma unroll
        for (int ni = 0; ni < 5; ni++)
            b[ni] = *(const short8*)(Wt + (size_t)(ni * 16 + r) * 128 + kc + q * 8);
#pragma unroll
        for (int ni = 0; ni < 5; ni++)
            acc[ni] = __builtin_amdgcn_mfma_f32_16x16x32_bf16(a, b[ni], acc[ni], 0, 0, 0);
    }

    int rowb = m0 + q * 4;
#pragma unroll
    for (int ni = 0; ni < 5; ni++) {
        int col = ni * 16 + r;
#pragma unroll
        for (int reg = 0; reg < 4; reg++) {
            int gr = rowb + reg;
            if (gr < N_NODES) {
                unsigned short v = f2bf(acc[ni][reg]);
                if (col < 40)
                    zlb[(size_t)gr * 40 + col] = v;
                else
                    zrb[(size_t)gr * 40 + (col - 40)] = v;
            }
        }
    }
}

// ---------------------------------------------------------------------------
// Fused agg + epilogue layer 1, FP8 gather (128 B/row), 8-deep unroll.
// ONE NODE PER WAVE (50k waves — gather throughput comes from wave count;
// r13's 16-nodes-per-wave fusion proved this the hard way):
//   h[n] = relu( (1/max(cnt,1)) * sum_j yl[bucket[n][j]] + yr[n] + b1 )
// ---------------------------------------------------------------------------
__global__ __launch_bounds__(256) void agg_relu1_kernel(
    const unsigned short* __restrict__ yl8, const int* __restrict__ cnt,
    const unsigned short* __restrict__ bucket, const float2* __restrict__ b12,
    const unsigned int* __restrict__ yru, unsigned int* __restrict__ hbu) {
    int n = blockIdx.x * 4 + (threadIdx.x >> 6);
    if (n >= N_NODES) return;
    int l = threadIdx.x & 63;
    int deg = cnt[n];
    int re = min(deg, CAP);
    const unsigned short* bk = bucket + n * CAP;
    float ax = 0.f, ay = 0.f, bx = 0.f, by = 0.f;
    int e = 0;
    for (; e + 7 < re; e += 8) {
        unsigned short u[8];
#pragma unroll
        for (int j = 0; j < 8; j++) {
            int s = bk[e + j];
            u[j] = yl8[(size_t)s * 64 + l];
        }
#pragma unroll
        for (int j = 0; j < 8; j += 2) {
            ax += fp82f(u[j] & 0xff); ay += fp82f(u[j] >> 8);
            bx += fp82f(u[j + 1] & 0xff); by += fp82f(u[j + 1] >> 8);
        }
    }
    for (; e + 3 < re; e += 4) {
        int s0 = bk[e + 0], s1 = bk[e + 1], s2 = bk[e + 2], s3 = bk[e + 3];
        unsigned short u0 = yl8[(size_t)s0 * 64 + l];
        unsigned short u1 = yl8[(size_t)s1 * 64 + l];
        unsigned short u2 = yl8[(size_t)s2 * 64 + l];
        unsigned short u3 = yl8[(size_t)s3 * 64 + l];
        ax += fp82f(u0 & 0xff); ay += fp82f(u0 >> 8);
        bx += fp82f(u1 & 0xff); by += fp82f(u1 >> 8);
        ax += fp82f(u2 & 0xff); ay += fp82f(u2 >> 8);
        bx += fp82f(u3 & 0xff); by += fp82f(u3 >> 8);
    }
    for (; e < re; e++) {
        unsigned short u0 = yl8[(size_t)bk[e] * 64 + l];
        ax += fp82f(u0 & 0xff); ay += fp82f(u0 >> 8);
    }
    float inv = 1.0f / (float)max(deg, 1);
    unsigned ur = yru[(size_t)n * 64 + l];
    float2 b = b12[l];
    float ox = fmaxf((ax + bx) * inv + bf2f(ur & 0xffff) + b.x, 0.0f);
    float oy = fmaxf((ay + by) * inv + bf2f(ur >> 16) + b.y, 0.0f);
    hbu[(size_t)n * 64 + l] = (unsigned)f2bf(ox) | ((unsigned)f2bf(oy) << 16);
}

// ---------------------------------------------------------------------------
// Fused agg + epilogue layer 2 (bf16 z), bucket traversal:
//   out[n][c] = (1/max(cnt,1)) * sum_j zl[bucket[n][j]][c] + zr[n][c] + b2[c]
// ---------------------------------------------------------------------------
__global__ __launch_bounds__(256) void agg_out2_kernel(
    const unsigned short* __restrict__ zlb, const unsigned short* __restrict__ zrb,
    const int* __restrict__ cnt, const unsigned short* __restrict__ bucket,
    const float* __restrict__ b2, float* __restrict__ out) {
    int n = blockIdx.x * 4 + (threadIdx.x >> 6);
    if (n >= N_NODES) return;
    int c = threadIdx.x & 63;
    if (c >= N_CLASSES) return;
    int deg = cnt[n];
    int re = min(deg, CAP);
    const unsigned short* bk = bucket + n * CAP;
    float a0 = 0.f, a1 = 0.f;
    int e = 0;
    for (; e + 3 < re; e += 4) {
        int s0 = bk[e + 0], s1 = bk[e + 1], s2 = bk[e + 2], s3 = bk[e + 3];
        float v0 = bf2f(zlb[(size_t)s0 * 40 + c]);
        float v1 = bf2f(zlb[(size_t)s1 * 40 + c]);
        float v2 = bf2f(zlb[(size_t)s2 * 40 + c]);
        float v3 = bf2f(zlb[(size_t)s3 * 40 + c]);
        a0 += v0 + v2;
        a1 += v1 + v3;
    }
    for (; e < re; e++) a0 += bf2f(zlb[(size_t)bk[e] * 40 + c]);
    float inv = 1.0f / (float)max(deg, 1);
    out[(size_t)n * 40 + c] =
        (a0 + a1) * inv + bf2f(zrb[(size_t)n * 40 + c]) + b2[c];
}

// ---------------------------------------------------------------------------
extern "C" void kernel_launch(void* const* d_in, const int* in_sizes, int n_in,
                              void* d_out, int out_size, void* d_ws, size_t ws_size,
                              hipStream_t stream) {
    const float* x   = (const float*)d_in[0];
    const int*   ei  = (const int*)d_in[1];   // [2, E]: src row then dst row
    const float* W1l = (const float*)d_in[2];
    const float* b1  = (const float*)d_in[3];
    const float* W1r = (const float*)d_in[4];
    const float* W2l = (const float*)d_in[5];
    const float* b2  = (const float*)d_in[6];
    const float* W2r = (const float*)d_in[7];
    float* out = (float*)d_out;

    const int* src = ei;
    const int* dst = ei + N_EDGES;

    // Workspace layout (bytes), strictly non-overlapping, 16B-aligned:
    //  cnt    @ 0            200,000   (pad to 262,144)
    //  bucket @ 262,144    6,400,000   ends  6,662,144  (ushort)
    //  Wt1    @ 6,662,144     65,536   ends  6,727,680
    //  Wt2    @ 6,727,680     20,480   ends  6,748,160
    //  hb     @ 6,748,160  12,812,288  ends 19,560,448  (M_PAD rows, bf16)
    //  ylb    @ 19,560,448  6,400,000  ends 25,960,448  (fp8 e4m3)
    //  yrb    @ 25,960,448 12,800,000  ends 38,760,448  (bf16)
    //  zlb    @ 38,760,448  4,000,000  ends 42,760,448  (bf16)
    //  zrb    @ 42,760,448  4,000,000  ends 46,760,448  (< 256 MiB)
    char* ws = (char*)d_ws;
    int* cnt               = (int*)(ws);
    unsigned short* bucket = (unsigned short*)(ws + 262144);
    unsigned short* Wt1    = (unsigned short*)(ws + 6662144);
    unsigned short* Wt2    = (unsigned short*)(ws + 6727680);
    unsigned short* hb     = (unsigned short*)(ws + 6748160);
    unsigned char*  ylb    = (unsigned char*)(ws + 19560448);
    unsigned short* yrb    = (unsigned short*)(ws + 25960448);
    unsigned short* zlb    = (unsigned short*)(ws + 38760448);
    unsigned short* zrb    = (unsigned short*)(ws + 42760448);

    // --- prep (weight transposes + cnt zero) + bucket build (1 atomic pass)
    prep_kernel<<<KP_GRID, 256, 0, stream>>>(W1l, W1r, Wt1, W2l, W2r, Wt2, cnt);
    fill_bucket_kernel<<<EDGE_BATCH_BLOCKS, 256, 0, stream>>>(src, dst, cnt,
                                                              bucket);

    const int AGG_BLOCKS = (N_NODES + 3) / 4;

    // --- Layer 1 (no-LDS gemm1: grid.y splits ylb/yrb col-halves)
    {
        dim3 grid(M_PAD / 64, 2);
        gemm1_mfma_kernel<<<grid, 256, 0, stream>>>(x, Wt1, ylb, yrb);
    }
    agg_relu1_kernel<<<AGG_BLOCKS, 256, 0, stream>>>(
        (const unsigned short*)ylb, cnt, bucket, (const float2*)b1,
        (const unsigned int*)yrb, (unsigned int*)hb);

    // --- Layer 2
    gemm2_mfma_kernel<<<M_PAD / 64, 256, 0, stream>>>(hb, Wt2, zlb, zrb);
    agg_out2_kernel<<<AGG_BLOCKS, 256, 0, stream>>>(
        zlb, zrb, cnt, bucket, b2, out);
}